// Round 28
// baseline (206.748 us; speedup 1.0000x reference)
//
#include <hip/hip_runtime.h>
#include <stdint.h>
#include <limits.h>

// StackMachineCell — fused, VALU-bitplane stack (round 28).
// r27 regressed (172us): scalar chain s_load shared lgkmcnt with the
// publish ds_write (r6 lesson, self-violated) + readlane input fetch.
// Revert to r26's producer (vector u16 LUT load, best: sm_fused ~128us)
// with ONE change: ds_bpermute (~120cy DS round-trip, on-chain every step)
// -> stack as 5 u64 bitplanes in VGPRs (wave-uniform values), ~18 VALU ops
// (~50cy, no lgkmcnt). Push = masked bit-set at npn; rr = bit-extract at
// npn. Case-identical to stack.at[npn].set + read (reference semantics).
// Everything else byte-identical to r26 (PASSED, e2e 152, absmax
// 0.0009765625): flag handoff (trajL==0xFFFF), 1P+7C, nt stores, setprio.
// ws: Mm32@0 | Ms32@17408 | Mb32@50176 | MmT@115712 | MsT@133120 |
//     lut@165888  (total 690176 B; guarded).

#define TT 512
#define BB 512
#define HH 128
#define NSs 64
#define NMm 34
#define NBb 128

typedef unsigned short u16;
typedef unsigned long long u64;
typedef float f2 __attribute__((ext_vector_type(2)));

// ---- precompute M tables (f64 accumulate, f32 store; + transposed copies)
__global__ __launch_bounds__(256) void precompute_M(
    const float* __restrict__ embed,
    const float* __restrict__ Wm, const float* __restrict__ bm,
    const float* __restrict__ Wb, const float* __restrict__ bb,
    const float* __restrict__ Ws, const float* __restrict__ bs,
    float* __restrict__ Mm32, float* __restrict__ Ms32,
    float* __restrict__ Mb32, float* __restrict__ MmT,
    float* __restrict__ MsT) {
  __shared__ double e[HH];
  const int v = blockIdx.x;
  const int tid = threadIdx.x;  // 256
  if (tid < HH) e[tid] = (double)embed[v * HH + tid];
  __syncthreads();
  if (tid < NMm) {
    const int j = tid;
    double acc = 0.0;
    for (int h = 0; h < HH; ++h) acc += e[h] * (double)Wm[h * NMm + j];
    const float r = (float)(acc + (double)bm[j]);
    Mm32[v * NMm + j] = r;
    MmT[j * 128 + v] = r;
  } else if (tid < NMm + NSs) {
    const int j = tid - NMm;
    double acc = 0.0;
    for (int h = 0; h < HH; ++h) acc += e[h] * (double)Ws[h * NSs + j];
    const float r = (float)(acc + (double)bs[j]);
    Ms32[v * NSs + j] = r;
    MsT[j * 128 + v] = r;
  } else if (tid < NMm + NSs + NBb) {
    const int j = tid - NMm - NSs;
    double acc = 0.0;
    for (int h = 0; h < HH; ++h) acc += e[h] * (double)Wb[h * NBb + j];
    Mb32[v * NBb + j] = (float)(acc + (double)bb[j]);
  }
}

// ---- build decision LUT: block = (s,r) pair, thread = v. Bit-identical
// arithmetic to r12-r27. Layout lut[(s*32+r)*128 + v] (u16).
__global__ __launch_bounds__(128) void build_lut(
    const float* __restrict__ Wm, const float* __restrict__ Ws,
    const float* __restrict__ MmT, const float* __restrict__ MsT,
    u16* __restrict__ lut) {
  __shared__ float wms[NMm], wmr[NMm], wss[NSs], wsr[NSs];  // 784 B
  const int s = blockIdx.x >> 5;    // 0..63
  const int r = blockIdx.x & 31;    // 0..31
  const int tid = threadIdx.x;      // 128 = one v per thread
  if (tid < NMm) {
    wms[tid] = Wm[(128 + s) * NMm + tid];
    wmr[tid] = Wm[(192 + r) * NMm + tid];
  }
  if (tid < NSs) {
    wss[tid] = Ws[(128 + s) * NSs + tid];
    wsr[tid] = Ws[(192 + r) * NSs + tid];
  }
  __syncthreads();

  const int v = tid;
  int bestm = INT_MIN, act = 0;
#pragma unroll
  for (int j = 0; j < NMm; ++j) {
    const double val = (double)MmT[j * 128 + v] + (double)wms[j] + (double)wmr[j];
    const int iv = (int)(val * 67108864.0);
    if (iv > bestm) { bestm = iv; act = j; }
  }
  int bests = INT_MIN, ns = 0;
#pragma unroll
  for (int j = 0; j < NSs; ++j) {
    const double val = (double)MsT[j * 128 + v] + (double)wss[j] + (double)wsr[j];
    const int iv = (int)(val * 67108864.0);
    if (iv > bests) { bests = iv; ns = j; }
  }
  lut[(unsigned)blockIdx.x * 128 + v] = (u16)(act | (ns << 6));
}

// ---- fused: 512 blocks x 512 threads, ONE chain per block.
// Wave 0 = producer (vector LUT load + VALU bitplane stack, setprio 1);
// waves 1-7 = consumers (rows t mod 7, sleep-4 backoff, nt stores).
// trajL doubles as progress flag (0xFFFF = not ready; legal <= 0x1F3F).
__global__ __launch_bounds__(512, 1) void sm_fused(
    const int* __restrict__ x, const int* __restrict__ tact,
    const int* __restrict__ tstate, const int* __restrict__ forc,
    const u16* __restrict__ lut,
    const float* __restrict__ Wm, const float* __restrict__ Wb,
    const float* __restrict__ Ws,
    const float* __restrict__ Mm32, const float* __restrict__ Ms32,
    const float* __restrict__ Mb32, float* __restrict__ out) {
  __shared__ unsigned sPk[TT];          // 2048 B
  __shared__ volatile u16 trajL[TT];    // 1024 B (flag+data in one u16)
  const int tid = threadIdx.x;
  const int b = blockIdx.x;
  for (int t = tid; t < TT; t += 512) {
    const int g = t * BB + b;
    sPk[t] = (unsigned)x[g] | ((unsigned)tact[g] << 8) |
             ((unsigned)tstate[g] << 16) | ((unsigned)forc[g] << 24);
    trajL[t] = 0xFFFFu;
  }
  __syncthreads();  // last barrier; roles diverge below

  const int lane = tid & 63;
  const int w = tid >> 6;

  if (w == 0) {
    // ===== producer: r26 chain with VALU bitplane stack ==================
    __builtin_amdgcn_s_setprio(1);
    u64 pl0 = 0, pl1 = 0, pl2 = 0, pl3 = 0, pl4 = 0;  // stack bitplanes
    int ptr = 0, rr = 0, s = 0;
    unsigned p0 = sPk[0], p1 = sPk[1], p2 = sPk[2];

    for (int t = 0; t < TT; ++t) {
      const unsigned p3 = sPk[t + 3 < TT ? t + 3 : TT - 1];
      const unsigned pk_s = __builtin_amdgcn_readfirstlane(p0);

      if (lane == 0) trajL[t] = (u16)(s | (rr << 8));  // publish carry-in

      int act, ns;
      if (pk_s >> 24) {  // forced: extract from VGPR p0, no LUT
        act = (int)((p0 >> 8) & 63u);
        ns = (int)((p0 >> 16) & 63u);
      } else {
        const int idx = s * 4096 + rr * 128 + (int)(p0 & 127u);
        const int lv = lut[idx];  // vector load, L2-hot — THE chain
        act = lv & 63;
        ns = (lv >> 6) & 63;
      }

      const bool ispush = act >= 2;
      int npn = ptr + (ispush ? 1 : 0) - (act == 1 ? 1 : 0);
      npn = npn < 0 ? 0 : (npn > 63 ? 63 : npn);
      if (ispush) {  // stack[npn] = sym: masked bit-set in 5 planes (VALU)
        const unsigned sym = (unsigned)(act - 2);
        const u64 m = ~(1ULL << npn);
        pl0 = (pl0 & m) | ((u64)(sym & 1u) << npn);
        pl1 = (pl1 & m) | ((u64)((sym >> 1) & 1u) << npn);
        pl2 = (pl2 & m) | ((u64)((sym >> 2) & 1u) << npn);
        pl3 = (pl3 & m) | ((u64)((sym >> 3) & 1u) << npn);
        pl4 = (pl4 & m) | ((u64)((sym >> 4) & 1u) << npn);
      }
      // rr = stack[npn]: bit-extract (VALU, no DS, no lgkm wait)
      rr = (int)(((pl0 >> npn) & 1) | (((pl1 >> npn) & 1) << 1) |
                 (((pl2 >> npn) & 1) << 2) | (((pl3 >> npn) & 1) << 3) |
                 (((pl4 >> npn) & 1) << 4));
      ptr = npn;
      s = ns;

      p0 = p1; p1 = p2; p2 = p3;
    }
  } else {
    // ======= consumer: 7 waves, rows t = j, j+7, ... (r26 verbatim) =====
    const int j = w - 1;   // 0..6
    float* outLM = out;                                  // [T,B,34]
    float* outLB = out + (size_t)TT * BB * NMm;          // [T,B,128]
    float* outLS = out + (size_t)TT * BB * (NMm + NBb);  // [T,B,64]

    for (int t = j; t < TT; t += 7) {
      int pr = trajL[t];
      while (pr == 0xFFFF) {            // flag: row not yet published
        __builtin_amdgcn_s_sleep(4);
        pr = trajL[t];
      }
      const unsigned pk = sPk[t];
      const int xv = (int)(pk & 127u);
      const int s = pr & 255;
      const int r = pr >> 8;
      const int rs = 128 + s, rr = 192 + r;
      const int row = t * BB + b;
      if (lane < NMm)
        __builtin_nontemporal_store(
            Mm32[xv * NMm + lane] + Wm[rs * NMm + lane] + Wm[rr * NMm + lane],
            &outLM[(size_t)row * NMm + lane]);
      __builtin_nontemporal_store(
          Ms32[xv * NSs + lane] + Ws[rs * NSs + lane] + Ws[rr * NSs + lane],
          &outLS[(size_t)row * NSs + lane]);
      const f2 mb  = *(const f2*)&Mb32[xv * NBb + 2 * lane];
      const f2 wbs = *(const f2*)&Wb[rs * NBb + 2 * lane];
      const f2 wbr = *(const f2*)&Wb[rr * NBb + 2 * lane];
      f2 o;
      o.x = mb.x + wbs.x + wbr.x;   // same per-element add order as r14-r27
      o.y = mb.y + wbs.y + wbr.y;
      __builtin_nontemporal_store(o, (f2*)&outLB[(size_t)row * NBb + 2 * lane]);
    }
  }
}

extern "C" void kernel_launch(void* const* d_in, const int* in_sizes, int n_in,
                              void* d_out, int out_size, void* d_ws, size_t ws_size,
                              hipStream_t stream) {
  if (ws_size < 690176) return;  // signature: absmax 0.3457 -> ws too small

  const int* x     = (const int*)d_in[0];
  const int* tactp = (const int*)d_in[1];
  const int* tstp  = (const int*)d_in[2];
  const int* forcp = (const int*)d_in[3];
  const float* embed = (const float*)d_in[4];
  const float* Wm = (const float*)d_in[5];
  const float* bm = (const float*)d_in[6];
  const float* Wb = (const float*)d_in[7];
  const float* bb = (const float*)d_in[8];
  const float* Ws = (const float*)d_in[9];
  const float* bs = (const float*)d_in[10];

  char* wsp = (char*)d_ws;
  float* Mm32 = (float*)(wsp);            //  17408 B
  float* Ms32 = (float*)(wsp + 17408);    //  32768 B
  float* Mb32 = (float*)(wsp + 50176);    //  65536 B
  float* MmT  = (float*)(wsp + 115712);   //  17408 B
  float* MsT  = (float*)(wsp + 133120);   //  32768 B
  u16*   lut  = (u16*)(wsp + 165888);     // 524288 B -> total 690176 B

  precompute_M<<<128, 256, 0, stream>>>(embed, Wm, bm, Wb, bb, Ws, bs,
                                        Mm32, Ms32, Mb32, MmT, MsT);
  build_lut<<<2048, 128, 0, stream>>>(Wm, Ws, MmT, MsT, lut);
  sm_fused<<<512, 512, 0, stream>>>(x, tactp, tstp, forcp, lut,
                                    Wm, Wb, Ws, Mm32, Ms32, Mb32,
                                    (float*)d_out);
}

// Round 29
// 167.630 us; speedup vs baseline: 1.2334x; 1.2334x over previous
//
#include <hip/hip_runtime.h>
#include <stdint.h>
#include <limits.h>

// StackMachineCell — fused, shadow-stack producer (round 29).
// r27/r28 chain surgeries regressed; r26 (e2e 152) is the base. This round
// removes the ds_bpermute WAIT from the chain without removing the bpermute:
// rr_new = stack_new[npn] is case-computable from two shadow registers
// (b = stack[ptr-1], c = stack[ptr-2]):
//   push: rr'=act-2 | pop(ptr>=1): rr'=b | pop(ptr=0)/noop: rr'=rr
//   b' = push ? (ptr==63 ? b : rr) : (pop&&ptr>0 ? c : b)
//   c' = stack[clamp(npn-2)]  <- ONE unconditional ds_bpermute per step,
//        consumed only next iteration (covered by iteration latency).
// Edge audit (push@63, pop@0/@1/@2): invalid shadows never read before
// overwrite; invariants hold from all-zero init. r25's PASS proved the
// rr==stack[ptr] invariant this construction extends.
// Everything else byte-identical to r26 (PASSED, absmax 0.0009765625):
// flag handoff (trajL==0xFFFF), 1P+7C, nt stores, setprio, vector u16 LUT.
// ws: Mm32@0 | Ms32@17408 | Mb32@50176 | MmT@115712 | MsT@133120 |
//     lut@165888  (total 690176 B; guarded).

#define TT 512
#define BB 512
#define HH 128
#define NSs 64
#define NMm 34
#define NBb 128

typedef unsigned short u16;
typedef float f2 __attribute__((ext_vector_type(2)));

// ---- precompute M tables (f64 accumulate, f32 store; + transposed copies)
__global__ __launch_bounds__(256) void precompute_M(
    const float* __restrict__ embed,
    const float* __restrict__ Wm, const float* __restrict__ bm,
    const float* __restrict__ Wb, const float* __restrict__ bb,
    const float* __restrict__ Ws, const float* __restrict__ bs,
    float* __restrict__ Mm32, float* __restrict__ Ms32,
    float* __restrict__ Mb32, float* __restrict__ MmT,
    float* __restrict__ MsT) {
  __shared__ double e[HH];
  const int v = blockIdx.x;
  const int tid = threadIdx.x;  // 256
  if (tid < HH) e[tid] = (double)embed[v * HH + tid];
  __syncthreads();
  if (tid < NMm) {
    const int j = tid;
    double acc = 0.0;
    for (int h = 0; h < HH; ++h) acc += e[h] * (double)Wm[h * NMm + j];
    const float r = (float)(acc + (double)bm[j]);
    Mm32[v * NMm + j] = r;
    MmT[j * 128 + v] = r;
  } else if (tid < NMm + NSs) {
    const int j = tid - NMm;
    double acc = 0.0;
    for (int h = 0; h < HH; ++h) acc += e[h] * (double)Ws[h * NSs + j];
    const float r = (float)(acc + (double)bs[j]);
    Ms32[v * NSs + j] = r;
    MsT[j * 128 + v] = r;
  } else if (tid < NMm + NSs + NBb) {
    const int j = tid - NMm - NSs;
    double acc = 0.0;
    for (int h = 0; h < HH; ++h) acc += e[h] * (double)Wb[h * NBb + j];
    Mb32[v * NBb + j] = (float)(acc + (double)bb[j]);
  }
}

// ---- build decision LUT: block = (s,r) pair, thread = v. Bit-identical
// arithmetic to r12-r28. Layout lut[(s*32+r)*128 + v] (u16).
__global__ __launch_bounds__(128) void build_lut(
    const float* __restrict__ Wm, const float* __restrict__ Ws,
    const float* __restrict__ MmT, const float* __restrict__ MsT,
    u16* __restrict__ lut) {
  __shared__ float wms[NMm], wmr[NMm], wss[NSs], wsr[NSs];  // 784 B
  const int s = blockIdx.x >> 5;    // 0..63
  const int r = blockIdx.x & 31;    // 0..31
  const int tid = threadIdx.x;      // 128 = one v per thread
  if (tid < NMm) {
    wms[tid] = Wm[(128 + s) * NMm + tid];
    wmr[tid] = Wm[(192 + r) * NMm + tid];
  }
  if (tid < NSs) {
    wss[tid] = Ws[(128 + s) * NSs + tid];
    wsr[tid] = Ws[(192 + r) * NSs + tid];
  }
  __syncthreads();

  const int v = tid;
  int bestm = INT_MIN, act = 0;
#pragma unroll
  for (int j = 0; j < NMm; ++j) {
    const double val = (double)MmT[j * 128 + v] + (double)wms[j] + (double)wmr[j];
    const int iv = (int)(val * 67108864.0);
    if (iv > bestm) { bestm = iv; act = j; }
  }
  int bests = INT_MIN, ns = 0;
#pragma unroll
  for (int j = 0; j < NSs; ++j) {
    const double val = (double)MsT[j * 128 + v] + (double)wss[j] + (double)wsr[j];
    const int iv = (int)(val * 67108864.0);
    if (iv > bests) { bests = iv; ns = j; }
  }
  lut[(unsigned)blockIdx.x * 128 + v] = (u16)(act | (ns << 6));
}

// ---- fused: 512 blocks x 512 threads, ONE chain per block.
// Wave 0 = producer (shadow-stack chain, setprio 1); waves 1-7 = consumers
// (rows t mod 7, sleep-4 backoff, nt stores). trajL doubles as flag.
__global__ __launch_bounds__(512, 1) void sm_fused(
    const int* __restrict__ x, const int* __restrict__ tact,
    const int* __restrict__ tstate, const int* __restrict__ forc,
    const u16* __restrict__ lut,
    const float* __restrict__ Wm, const float* __restrict__ Wb,
    const float* __restrict__ Ws,
    const float* __restrict__ Mm32, const float* __restrict__ Ms32,
    const float* __restrict__ Mb32, float* __restrict__ out) {
  __shared__ unsigned sPk[TT];          // 2048 B
  __shared__ volatile u16 trajL[TT];    // 1024 B (flag+data in one u16)
  const int tid = threadIdx.x;
  const int b = blockIdx.x;
  for (int t = tid; t < TT; t += 512) {
    const int g = t * BB + b;
    sPk[t] = (unsigned)x[g] | ((unsigned)tact[g] << 8) |
             ((unsigned)tstate[g] << 16) | ((unsigned)forc[g] << 24);
    trajL[t] = 0xFFFFu;
  }
  __syncthreads();  // last barrier; roles diverge below

  const int lane = tid & 63;
  const int w = tid >> 6;

  if (w == 0) {
    // ===== producer: chain never waits on the bpermute ==================
    __builtin_amdgcn_s_setprio(1);
    int stackv = 0;  // lane i holds stack[i]
    int ptr = 0, s = 0;
    int a = 0, bsh = 0, csh = 0;  // a=stack[ptr](==rr), b=stack[ptr-1], c=stack[ptr-2]
    unsigned p0 = sPk[0], p1 = sPk[1], p2 = sPk[2];

    for (int t = 0; t < TT; ++t) {
      const unsigned p3 = sPk[t + 3 < TT ? t + 3 : TT - 1];
      const unsigned pk_s = __builtin_amdgcn_readfirstlane(p0);

      if (lane == 0) trajL[t] = (u16)(s | (a << 8));  // publish carry-in

      int act, ns;
      if (pk_s >> 24) {  // forced: extract from VGPR p0, no LUT
        act = (int)((p0 >> 8) & 63u);
        ns = (int)((p0 >> 16) & 63u);
      } else {
        const int idx = s * 4096 + a * 128 + (int)(p0 & 127u);
        const int lv = lut[idx];  // THE chain: load -> selects -> next load
        act = lv & 63;
        ns = (lv >> 6) & 63;
      }

      const bool ispush = act >= 2;
      const bool ispop = act == 1;
      int npn = ptr + (ispush ? 1 : 0) - (ispop ? 1 : 0);
      npn = npn < 0 ? 0 : (npn > 63 ? 63 : npn);
      if (ispush && lane == npn) stackv = act - 2;

      // rr' and shadow updates — pure VALU selects, no stack read:
      const bool popv = ispop && (ptr > 0);
      const int na = ispush ? (act - 2) : (popv ? bsh : a);
      const int nb = ispush ? (ptr == 63 ? bsh : a) : (popv ? csh : bsh);
      // c' = stack_new[clamp(npn-2)] — refill via bpermute, consumed only
      // next iteration (its wait is covered by the iteration latency)
      int fi = npn - 2;
      fi = fi < 0 ? 0 : fi;
      csh = __builtin_amdgcn_ds_bpermute(fi * 4, stackv);
      a = na;
      bsh = nb;
      ptr = npn;
      s = ns;

      p0 = p1; p1 = p2; p2 = p3;
    }
  } else {
    // ======= consumer: 7 waves, rows t = j, j+7, ... (r26 verbatim) =====
    const int j = w - 1;   // 0..6
    float* outLM = out;                                  // [T,B,34]
    float* outLB = out + (size_t)TT * BB * NMm;          // [T,B,128]
    float* outLS = out + (size_t)TT * BB * (NMm + NBb);  // [T,B,64]

    for (int t = j; t < TT; t += 7) {
      int pr = trajL[t];
      while (pr == 0xFFFF) {            // flag: row not yet published
        __builtin_amdgcn_s_sleep(4);
        pr = trajL[t];
      }
      const unsigned pk = sPk[t];
      const int xv = (int)(pk & 127u);
      const int s = pr & 255;
      const int r = pr >> 8;
      const int rs = 128 + s, rr = 192 + r;
      const int row = t * BB + b;
      if (lane < NMm)
        __builtin_nontemporal_store(
            Mm32[xv * NMm + lane] + Wm[rs * NMm + lane] + Wm[rr * NMm + lane],
            &outLM[(size_t)row * NMm + lane]);
      __builtin_nontemporal_store(
          Ms32[xv * NSs + lane] + Ws[rs * NSs + lane] + Ws[rr * NSs + lane],
          &outLS[(size_t)row * NSs + lane]);
      const f2 mb  = *(const f2*)&Mb32[xv * NBb + 2 * lane];
      const f2 wbs = *(const f2*)&Wb[rs * NBb + 2 * lane];
      const f2 wbr = *(const f2*)&Wb[rr * NBb + 2 * lane];
      f2 o;
      o.x = mb.x + wbs.x + wbr.x;   // same per-element add order as r14-r28
      o.y = mb.y + wbs.y + wbr.y;
      __builtin_nontemporal_store(o, (f2*)&outLB[(size_t)row * NBb + 2 * lane]);
    }
  }
}

extern "C" void kernel_launch(void* const* d_in, const int* in_sizes, int n_in,
                              void* d_out, int out_size, void* d_ws, size_t ws_size,
                              hipStream_t stream) {
  if (ws_size < 690176) return;  // signature: absmax 0.3457 -> ws too small

  const int* x     = (const int*)d_in[0];
  const int* tactp = (const int*)d_in[1];
  const int* tstp  = (const int*)d_in[2];
  const int* forcp = (const int*)d_in[3];
  const float* embed = (const float*)d_in[4];
  const float* Wm = (const float*)d_in[5];
  const float* bm = (const float*)d_in[6];
  const float* Wb = (const float*)d_in[7];
  const float* bb = (const float*)d_in[8];
  const float* Ws = (const float*)d_in[9];
  const float* bs = (const float*)d_in[10];

  char* wsp = (char*)d_ws;
  float* Mm32 = (float*)(wsp);            //  17408 B
  float* Ms32 = (float*)(wsp + 17408);    //  32768 B
  float* Mb32 = (float*)(wsp + 50176);    //  65536 B
  float* MmT  = (float*)(wsp + 115712);   //  17408 B
  float* MsT  = (float*)(wsp + 133120);   //  32768 B
  u16*   lut  = (u16*)(wsp + 165888);     // 524288 B -> total 690176 B

  precompute_M<<<128, 256, 0, stream>>>(embed, Wm, bm, Wb, bb, Ws, bs,
                                        Mm32, Ms32, Mb32, MmT, MsT);
  build_lut<<<2048, 128, 0, stream>>>(Wm, Ws, MmT, MsT, lut);
  sm_fused<<<512, 512, 0, stream>>>(x, tactp, tstp, forcp, lut,
                                    Wm, Wb, Ws, Mm32, Ms32, Mb32,
                                    (float*)d_out);
}

// Round 30
// 140.884 us; speedup vs baseline: 1.4675x; 1.1898x over previous
//
#include <hip/hip_runtime.h>
#include <stdint.h>
#include <limits.h>

// StackMachineCell — fused + XCD-local L2 warmup (round 30).
// r27/r28/r29 all removed the bpermute from the chain and ALL regressed ->
// the chain was never the bpermute. FETCH_SIZE ~19MB/dispatch = ~16MB of
// LUT line fetches = EVERY producer LUT load misses L2: build_lut's writes
// allocate each line only in the WRITING XCD's L2 (per-XCD L2s, not
// coherent), so a producer hits its local L2 with p~1/8 -> ~900-1100cy
// per non-forced step. Fix: consumers (idle at start) stream the full
// 512KB LUT via uint4 reads first, warming the LOCAL XCD L2; producer then
// sees ~225cy loads. r26 base verbatim otherwise (PASSED, e2e 152,
// absmax 0.0009765625): flag handoff, 1P+7C, nt stores, setprio.
// ws: Mm32@0 | Ms32@17408 | Mb32@50176 | MmT@115712 | MsT@133120 |
//     lut@165888  (total 690176 B; guarded).

#define TT 512
#define BB 512
#define HH 128
#define NSs 64
#define NMm 34
#define NBb 128

typedef unsigned short u16;
typedef float f2 __attribute__((ext_vector_type(2)));

// ---- precompute M tables (f64 accumulate, f32 store; + transposed copies)
__global__ __launch_bounds__(256) void precompute_M(
    const float* __restrict__ embed,
    const float* __restrict__ Wm, const float* __restrict__ bm,
    const float* __restrict__ Wb, const float* __restrict__ bb,
    const float* __restrict__ Ws, const float* __restrict__ bs,
    float* __restrict__ Mm32, float* __restrict__ Ms32,
    float* __restrict__ Mb32, float* __restrict__ MmT,
    float* __restrict__ MsT) {
  __shared__ double e[HH];
  const int v = blockIdx.x;
  const int tid = threadIdx.x;  // 256
  if (tid < HH) e[tid] = (double)embed[v * HH + tid];
  __syncthreads();
  if (tid < NMm) {
    const int j = tid;
    double acc = 0.0;
    for (int h = 0; h < HH; ++h) acc += e[h] * (double)Wm[h * NMm + j];
    const float r = (float)(acc + (double)bm[j]);
    Mm32[v * NMm + j] = r;
    MmT[j * 128 + v] = r;
  } else if (tid < NMm + NSs) {
    const int j = tid - NMm;
    double acc = 0.0;
    for (int h = 0; h < HH; ++h) acc += e[h] * (double)Ws[h * NSs + j];
    const float r = (float)(acc + (double)bs[j]);
    Ms32[v * NSs + j] = r;
    MsT[j * 128 + v] = r;
  } else if (tid < NMm + NSs + NBb) {
    const int j = tid - NMm - NSs;
    double acc = 0.0;
    for (int h = 0; h < HH; ++h) acc += e[h] * (double)Wb[h * NBb + j];
    Mb32[v * NBb + j] = (float)(acc + (double)bb[j]);
  }
}

// ---- build decision LUT: block = (s,r) pair, thread = v. Bit-identical
// arithmetic to r12-r29. Layout lut[(s*32+r)*128 + v] (u16).
__global__ __launch_bounds__(128) void build_lut(
    const float* __restrict__ Wm, const float* __restrict__ Ws,
    const float* __restrict__ MmT, const float* __restrict__ MsT,
    u16* __restrict__ lut) {
  __shared__ float wms[NMm], wmr[NMm], wss[NSs], wsr[NSs];  // 784 B
  const int s = blockIdx.x >> 5;    // 0..63
  const int r = blockIdx.x & 31;    // 0..31
  const int tid = threadIdx.x;      // 128 = one v per thread
  if (tid < NMm) {
    wms[tid] = Wm[(128 + s) * NMm + tid];
    wmr[tid] = Wm[(192 + r) * NMm + tid];
  }
  if (tid < NSs) {
    wss[tid] = Ws[(128 + s) * NSs + tid];
    wsr[tid] = Ws[(192 + r) * NSs + tid];
  }
  __syncthreads();

  const int v = tid;
  int bestm = INT_MIN, act = 0;
#pragma unroll
  for (int j = 0; j < NMm; ++j) {
    const double val = (double)MmT[j * 128 + v] + (double)wms[j] + (double)wmr[j];
    const int iv = (int)(val * 67108864.0);
    if (iv > bestm) { bestm = iv; act = j; }
  }
  int bests = INT_MIN, ns = 0;
#pragma unroll
  for (int j = 0; j < NSs; ++j) {
    const double val = (double)MsT[j * 128 + v] + (double)wss[j] + (double)wsr[j];
    const int iv = (int)(val * 67108864.0);
    if (iv > bests) { bests = iv; ns = j; }
  }
  lut[(unsigned)blockIdx.x * 128 + v] = (u16)(act | (ns << 6));
}

// ---- fused: 512 blocks x 512 threads, ONE chain per block.
// Wave 0 = producer (r26 chain verbatim, setprio 1); waves 1-7 = consumers
// (LUT warmup sweep, then rows t mod 7; nt stores). trajL doubles as flag.
__global__ __launch_bounds__(512, 1) void sm_fused(
    const int* __restrict__ x, const int* __restrict__ tact,
    const int* __restrict__ tstate, const int* __restrict__ forc,
    const u16* __restrict__ lut,
    const float* __restrict__ Wm, const float* __restrict__ Wb,
    const float* __restrict__ Ws,
    const float* __restrict__ Mm32, const float* __restrict__ Ms32,
    const float* __restrict__ Mb32, float* __restrict__ out) {
  __shared__ unsigned sPk[TT];          // 2048 B
  __shared__ volatile u16 trajL[TT];    // 1024 B (flag+data in one u16)
  const int tid = threadIdx.x;
  const int b = blockIdx.x;
  for (int t = tid; t < TT; t += 512) {
    const int g = t * BB + b;
    sPk[t] = (unsigned)x[g] | ((unsigned)tact[g] << 8) |
             ((unsigned)tstate[g] << 16) | ((unsigned)forc[g] << 24);
    trajL[t] = 0xFFFFu;
  }
  __syncthreads();  // last barrier; roles diverge below

  const int lane = tid & 63;
  const int w = tid >> 6;

  if (w == 0) {
    // ===== producer: r26 chain verbatim =================================
    __builtin_amdgcn_s_setprio(1);
    int stackv = 0;  // lane i holds stack[i]
    int ptr = 0, rr = 0, s = 0;
    unsigned p0 = sPk[0], p1 = sPk[1], p2 = sPk[2];

    for (int t = 0; t < TT; ++t) {
      const unsigned p3 = sPk[t + 3 < TT ? t + 3 : TT - 1];
      const unsigned pk_s = __builtin_amdgcn_readfirstlane(p0);

      if (lane == 0) trajL[t] = (u16)(s | (rr << 8));  // publish carry-in

      int act, ns;
      if (pk_s >> 24) {  // forced: extract from VGPR p0, no LUT
        act = (int)((p0 >> 8) & 63u);
        ns = (int)((p0 >> 16) & 63u);
      } else {
        const int idx = s * 4096 + rr * 128 + (int)(p0 & 127u);
        const int lv = lut[idx];  // vector load — L2-warm after sweep
        act = lv & 63;
        ns = (lv >> 6) & 63;
      }

      const bool ispush = act >= 2;
      int npn = ptr + (ispush ? 1 : 0) - (act == 1 ? 1 : 0);
      npn = npn < 0 ? 0 : (npn > 63 ? 63 : npn);
      if (ispush && lane == npn) stackv = act - 2;
      rr = __builtin_amdgcn_ds_bpermute(npn * 4, stackv);
      ptr = npn;
      s = ns;

      p0 = p1; p1 = p2; p2 = p3;
    }
  } else {
    // ======= consumer: warm local-XCD L2 with the LUT, then rows ========
    const int j = w - 1;   // 0..6
    const int cidx = j * 64 + lane;  // 0..447
    // LUT warmup sweep: 512KB as 32768 uint4; coalesced per-wave reads.
    {
      const uint4* lut4 = (const uint4*)lut;
      unsigned acc = 0;
      for (int i = cidx; i < 32768; i += 448) {
        const uint4 vv = lut4[i];
        acc ^= vv.x ^ vv.y ^ vv.z ^ vv.w;
      }
      asm volatile("" : : "v"(acc));  // keep the sweep alive (no DCE)
    }

    float* outLM = out;                                  // [T,B,34]
    float* outLB = out + (size_t)TT * BB * NMm;          // [T,B,128]
    float* outLS = out + (size_t)TT * BB * (NMm + NBb);  // [T,B,64]

    for (int t = j; t < TT; t += 7) {
      int pr = trajL[t];
      while (pr == 0xFFFF) {            // flag: row not yet published
        __builtin_amdgcn_s_sleep(4);
        pr = trajL[t];
      }
      const unsigned pk = sPk[t];
      const int xv = (int)(pk & 127u);
      const int s = pr & 255;
      const int r = pr >> 8;
      const int rs = 128 + s, rr = 192 + r;
      const int row = t * BB + b;
      if (lane < NMm)
        __builtin_nontemporal_store(
            Mm32[xv * NMm + lane] + Wm[rs * NMm + lane] + Wm[rr * NMm + lane],
            &outLM[(size_t)row * NMm + lane]);
      __builtin_nontemporal_store(
          Ms32[xv * NSs + lane] + Ws[rs * NSs + lane] + Ws[rr * NSs + lane],
          &outLS[(size_t)row * NSs + lane]);
      const f2 mb  = *(const f2*)&Mb32[xv * NBb + 2 * lane];
      const f2 wbs = *(const f2*)&Wb[rs * NBb + 2 * lane];
      const f2 wbr = *(const f2*)&Wb[rr * NBb + 2 * lane];
      f2 o;
      o.x = mb.x + wbs.x + wbr.x;   // same per-element add order as r14-r29
      o.y = mb.y + wbs.y + wbr.y;
      __builtin_nontemporal_store(o, (f2*)&outLB[(size_t)row * NBb + 2 * lane]);
    }
  }
}

extern "C" void kernel_launch(void* const* d_in, const int* in_sizes, int n_in,
                              void* d_out, int out_size, void* d_ws, size_t ws_size,
                              hipStream_t stream) {
  if (ws_size < 690176) return;  // signature: absmax 0.3457 -> ws too small

  const int* x     = (const int*)d_in[0];
  const int* tactp = (const int*)d_in[1];
  const int* tstp  = (const int*)d_in[2];
  const int* forcp = (const int*)d_in[3];
  const float* embed = (const float*)d_in[4];
  const float* Wm = (const float*)d_in[5];
  const float* bm = (const float*)d_in[6];
  const float* Wb = (const float*)d_in[7];
  const float* bb = (const float*)d_in[8];
  const float* Ws = (const float*)d_in[9];
  const float* bs = (const float*)d_in[10];

  char* wsp = (char*)d_ws;
  float* Mm32 = (float*)(wsp);            //  17408 B
  float* Ms32 = (float*)(wsp + 17408);    //  32768 B
  float* Mb32 = (float*)(wsp + 50176);    //  65536 B
  float* MmT  = (float*)(wsp + 115712);   //  17408 B
  float* MsT  = (float*)(wsp + 133120);   //  32768 B
  u16*   lut  = (u16*)(wsp + 165888);     // 524288 B -> total 690176 B

  precompute_M<<<128, 256, 0, stream>>>(embed, Wm, bm, Wb, bb, Ws, bs,
                                        Mm32, Ms32, Mb32, MmT, MsT);
  build_lut<<<2048, 128, 0, stream>>>(Wm, Ws, MmT, MsT, lut);
  sm_fused<<<512, 512, 0, stream>>>(x, tactp, tstp, forcp, lut,
                                    Wm, Wb, Ws, Mm32, Ms32, Mb32,
                                    (float*)d_out);
}